// Round 7
// baseline (135.105 us; speedup 1.0000x reference)
//
#include <hip/hip_runtime.h>

typedef unsigned short u16;
typedef float f32x4 __attribute__((ext_vector_type(4)));
typedef __bf16 bf16x8 __attribute__((ext_vector_type(8)));
typedef unsigned short u16x8 __attribute__((ext_vector_type(8)));
typedef unsigned short u16x4 __attribute__((ext_vector_type(4)));

#define DEV static __device__ __forceinline__

DEV u16 f2bf(float f) {
  unsigned int u = __float_as_uint(f);
  u += 0x7FFFu + ((u >> 16) & 1u);   // round-to-nearest-even
  return (u16)(u >> 16);
}
DEV float bf2f(u16 h) { return __uint_as_float(((unsigned int)h) << 16); }

// async global->LDS, 16B per lane. LDS dest = wave-uniform base + lane*16.
DEV void gload_lds16(const void* g, void* l) {
  __builtin_amdgcn_global_load_lds(
      (__attribute__((address_space(1))) void*)(unsigned long long)g,
      (__attribute__((address_space(3))) void*)l, 16, 0, 0);
}

// counted vmcnt wait; n is compile-time constant after full unroll
DEV void vm_wait(int n) {
  switch (n) {
    case 0:  asm volatile("s_waitcnt vmcnt(0)" ::: "memory"); break;
    case 4:  asm volatile("s_waitcnt vmcnt(4)" ::: "memory"); break;
    case 6:  asm volatile("s_waitcnt vmcnt(6)" ::: "memory"); break;
    case 8:  asm volatile("s_waitcnt vmcnt(8)" ::: "memory"); break;
    case 10: asm volatile("s_waitcnt vmcnt(10)" ::: "memory"); break;
    default: asm volatile("s_waitcnt vmcnt(14)" ::: "memory"); break;
  }
}

// ---------------------------------------------------------------------------
// K0b: convert w_qkv fp32 -> bf16
__global__ __launch_bounds__(256) void convert_w_kernel(
    const float* __restrict__ in, u16* __restrict__ out, int n) {
  int i = blockIdx.x * 256 + threadIdx.x;
  if (i < n) out[i] = f2bf(in[i]);
}

// ---------------------------------------------------------------------------
// B^T GEMM, fused A-transpose, DOUBLE-BUFFERED B with counted vmcnt
// (prefetch 2 tiles ahead; B_{j+1} is always a full iteration old at its
// wait -> no latency stall; stores ride 2 iters deep; no vmcnt(0) in loop).
// C[j][m] = sum_k A^T[m][k]*B[j][k], K=192. BM=64, BN=64, 4 waves (2m x 2n).
// LDS: sA 24 KB + sB0 24 KB + sB1 24 KB = 72 KB -> 2 blocks/CU.
template <bool IN_F32, bool OUT_BF16, int NJ>
__global__ __launch_bounds__(256, 2) void gemm_bt_kernel(
    const void* __restrict__ Av, const u16* __restrict__ B,
    void* __restrict__ Cv, size_t aBatch, size_t bBatch, size_t cBatch,
    int ldC) {
  __shared__ __align__(16) char smem[73728];
  char* sA = smem;  // [64][384B] content-swizzled

  const int tid = threadIdx.x, wave = tid >> 6, lane = tid & 63;
  const int id = blockIdx.x;
  const int m0 = (id & 255) * 64, b = id >> 8;
  const char* Bbase = (const char*)(B + (size_t)b * bBatch);

  // ---- A-stage part 1: issue ALL global loads to regs FIRST (so the
  // compiler's wait before the transpose leaves the B gloads outstanding)
  f32x4 vaf[3][4];
  u16x8 vau[2][4];
  if (IN_F32) {
    const float* Xb = (const float*)Av + (size_t)b * aBatch + m0;
    const int cbl = tid & 15, iq = tid >> 4;
#pragma unroll
    for (int p = 0; p < 3; ++p)
#pragma unroll
      for (int r = 0; r < 4; ++r)
        vaf[p][r] = *(const f32x4*)(Xb + (size_t)((p * 16 + cbl) * 4 + r) *
                                             16384 + iq * 4);
  } else {
    const u16* Vb = (const u16*)Av + (size_t)b * aBatch + m0;
#pragma unroll
    for (int p = 0; p < 2; ++p) {
      const int task = p * 256 + tid;  // 48 c-quads x 8 n-octs
      if (task < 384) {
        const int cb = task >> 3, io = task & 7;
#pragma unroll
        for (int r = 0; r < 4; ++r)
          vau[p][r] = *(const u16x8*)(Vb + (size_t)(cb * 4 + r) * 16384 +
                                      io * 8);
      }
    }
  }
  // ---- stage B0 -> buf0, B1 -> buf1 (12 gload_lds outstanding)
#pragma unroll
  for (int t = 0; t < 2; ++t) {
    if (t < NJ) {
      const char* Bj = Bbase + (size_t)t * 24576;
      char* sB = smem + 24576 + t * 24576;
#pragma unroll
      for (int i = 0; i < 6; ++i) {
        const int c = i * 4 + wave;
        const int d = c * 1024 + lane * 16;
        const int row = d / 384, inrow = d - row * 384;
        gload_lds16(Bj + row * 384 + (inrow ^ ((row & 7) << 4)), sB + c * 1024);
      }
    }
  }
  // ---- A-stage part 2: transpose + convert + swizzled ds_write
  if (IN_F32) {
    const int cbl = tid & 15, iq = tid >> 4;
#pragma unroll
    for (int p = 0; p < 3; ++p) {
      const int cb = p * 16 + cbl;
#pragma unroll
      for (int j = 0; j < 4; ++j) {
        const int n = iq * 4 + j;
        u16x4 col;
        col[0] = f2bf(vaf[p][0][j]);
        col[1] = f2bf(vaf[p][1][j]);
        col[2] = f2bf(vaf[p][2][j]);
        col[3] = f2bf(vaf[p][3][j]);
        *(u16x4*)(sA + n * 384 + ((cb * 8) ^ ((n & 7) << 4))) = col;
      }
    }
  } else {
#pragma unroll
    for (int p = 0; p < 2; ++p) {
      const int task = p * 256 + tid;
      if (task < 384) {
        const int cb = task >> 3, io = task & 7;
#pragma unroll
        for (int j = 0; j < 8; ++j) {
          const int n = io * 8 + j;
          u16x4 col;
          col[0] = vau[p][0][j];
          col[1] = vau[p][1][j];
          col[2] = vau[p][2][j];
          col[3] = vau[p][3][j];
          *(u16x4*)(sA + n * 384 + ((cb * 8) ^ ((n & 7) << 4))) = col;
        }
      }
    }
  }
  asm volatile("s_waitcnt lgkmcnt(0)" ::: "memory");  // A ds_writes done
  vm_wait(6);                                         // B0 landed (B1 in flight)
  __builtin_amdgcn_s_barrier();

  const int wm = wave & 1, wn = wave >> 1;
  const int l15 = lane & 15, lg = lane >> 4;
  const int swm = (l15 & 7) << 4;
  const int rA0 = (wm * 32 + l15) * 384;
  const int rB0 = (wn * 32 + l15) * 384;

  // ---- A fragments to registers, reused for all j
  bf16x8 af[2][6];
#pragma unroll
  for (int mi = 0; mi < 2; ++mi)
#pragma unroll
    for (int ks = 0; ks < 6; ++ks)
      af[mi][ks] = *(const bf16x8*)(sA + rA0 + mi * 16 * 384 +
                                    ((ks * 64 + lg * 16) ^ swm));

  f32x4 acc[2][2];
#pragma unroll
  for (int j = 0; j < NJ; ++j) {
    char* sB = smem + 24576 + ((j & 1) ? 24576 : 0);
    // read B_j fragments
    bf16x8 bfv[2][6];
#pragma unroll
    for (int nj = 0; nj < 2; ++nj)
#pragma unroll
      for (int ks = 0; ks < 6; ++ks)
        bfv[nj][ks] = *(const bf16x8*)(sB + rB0 + nj * 16 * 384 +
                                       ((ks * 64 + lg * 16) ^ swm));
    asm volatile("s_waitcnt lgkmcnt(0)" ::: "memory");
    __builtin_amdgcn_s_barrier();  // all waves done reading buf[j&1]
    // prefetch B_{j+2} into the buffer just freed
    if (j + 2 < NJ) {
      const char* Bj = Bbase + (size_t)(j + 2) * 24576;
#pragma unroll
      for (int i = 0; i < 6; ++i) {
        const int c = i * 4 + wave;
        const int d = c * 1024 + lane * 16;
        const int row = d / 384, inrow = d - row * 384;
        gload_lds16(Bj + row * 384 + (inrow ^ ((row & 7) << 4)), sB + c * 1024);
      }
    }
    // store tile j-1 (rides in flight for ~2 iterations)
    if (j > 0) {
      const int j0 = (j - 1) * 64;
      if (OUT_BF16) {
        u16* Cb = (u16*)Cv + (size_t)b * cBatch;
#pragma unroll
        for (int mi = 0; mi < 2; ++mi)
#pragma unroll
          for (int nj = 0; nj < 2; ++nj) {
            u16x4 ov;
#pragma unroll
            for (int r = 0; r < 4; ++r) ov[r] = f2bf(acc[mi][nj][r]);
            *(u16x4*)(Cb + (size_t)(j0 + wn * 32 + nj * 16 + l15) * ldC + m0 +
                      wm * 32 + mi * 16 + lg * 4) = ov;
          }
      } else {
        float* Cb = (float*)Cv + (size_t)b * cBatch;
#pragma unroll
        for (int mi = 0; mi < 2; ++mi)
#pragma unroll
          for (int nj = 0; nj < 2; ++nj)
            *(f32x4*)(Cb + (size_t)(j0 + wn * 32 + nj * 16 + l15) * ldC + m0 +
                      wm * 32 + mi * 16 + lg * 4) = acc[mi][nj];
      }
    }
    __builtin_amdgcn_sched_barrier(0);  // pin: loads+stores issued before MFMA
#pragma unroll
    for (int mi = 0; mi < 2; ++mi)
#pragma unroll
      for (int nj = 0; nj < 2; ++nj) acc[mi][nj] = (f32x4){0.f, 0.f, 0.f, 0.f};
#pragma unroll
    for (int ks = 0; ks < 6; ++ks)
#pragma unroll
      for (int mi = 0; mi < 2; ++mi)
#pragma unroll
        for (int nj = 0; nj < 2; ++nj)
          acc[mi][nj] = __builtin_amdgcn_mfma_f32_16x16x32_bf16(
              af[mi][ks], bfv[nj][ks], acc[mi][nj], 0, 0, 0);
    if (j + 1 < NJ) {
      // require only B_{j+1} complete (issued a full iteration ago).
      // newer-than-B_{j+1} in FIFO: st_{j-2}(4) + B_{j+2}(6) + st_{j-1}(4)
      vm_wait((j >= 2 ? 4 : 0) + (j + 3 < NJ ? 6 : 0) + (j >= 1 ? 4 : 0));
      __builtin_amdgcn_s_barrier();
    }
  }
  // final tile store
  {
    const int j0 = (NJ - 1) * 64;
    if (OUT_BF16) {
      u16* Cb = (u16*)Cv + (size_t)b * cBatch;
#pragma unroll
      for (int mi = 0; mi < 2; ++mi)
#pragma unroll
        for (int nj = 0; nj < 2; ++nj) {
          u16x4 ov;
#pragma unroll
          for (int r = 0; r < 4; ++r) ov[r] = f2bf(acc[mi][nj][r]);
          *(u16x4*)(Cb + (size_t)(j0 + wn * 32 + nj * 16 + l15) * ldC + m0 +
                    wm * 32 + mi * 16 + lg * 4) = ov;
        }
    } else {
      float* Cb = (float*)Cv + (size_t)b * cBatch;
#pragma unroll
      for (int mi = 0; mi < 2; ++mi)
#pragma unroll
        for (int nj = 0; nj < 2; ++nj)
          *(f32x4*)(Cb + (size_t)(j0 + wn * 32 + nj * 16 + l15) * ldC + m0 +
                    wm * 32 + mi * 16 + lg * 4) = acc[mi][nj];
    }
  }
}

// ---------------------------------------------------------------------------
// Depthwise 3x3 (pad 1), in-place on bf16 [b][576][128][128]; per-channel
// sum-of-squares for the q/k L2 norms. One block per (b, channel).
__global__ __launch_bounds__(256) void dwconv_kernel(
    u16* __restrict__ qkv, const float* __restrict__ wdw,
    float* __restrict__ sq) {
  __shared__ u16 img[16384];  // full 128x128 channel, 32 KB
  __shared__ float red[4];
  const int o = blockIdx.x, b = blockIdx.y;
  const size_t base = ((size_t)b * 576 + o) * 16384;
  const int tid = threadIdx.x, wave = tid >> 6, lane = tid & 63;
#pragma unroll
  for (int i = 0; i < 8; ++i) {
    const int off = (i * 4 + wave) * 1024;
    gload_lds16((const char*)qkv + base * 2 + off + lane * 16, (char*)img + off);
  }
  asm volatile("s_waitcnt vmcnt(0)" ::: "memory");
  __syncthreads();
  float w[9];
#pragma unroll
  for (int j = 0; j < 9; ++j) w[j] = wdw[o * 9 + j];
  float sqacc = 0.f;
  for (int it = 0; it < 8; ++it) {
    const int chunk = it * 256 + tid;  // 2048 chunks of 8 px
    const int px0 = chunk * 8;
    const int y = px0 >> 7, x0 = px0 & 127;
    float acc[8];
#pragma unroll
    for (int j = 0; j < 8; ++j) acc[j] = 0.f;
#pragma unroll
    for (int dy = -1; dy <= 1; ++dy) {
      const int yy = y + dy;
      float v[10];
      if (yy >= 0 && yy <= 127) {
        const u16* rowp = img + yy * 128 + x0;
        u16x8 m = *(const u16x8*)rowp;
#pragma unroll
        for (int j = 0; j < 8; ++j) v[j + 1] = bf2f(m[j]);
        v[0] = (x0 > 0) ? bf2f(rowp[-1]) : 0.f;
        v[9] = (x0 < 120) ? bf2f(rowp[8]) : 0.f;
      } else {
#pragma unroll
        for (int j = 0; j < 10; ++j) v[j] = 0.f;
      }
      const float w0 = w[(dy + 1) * 3], w1 = w[(dy + 1) * 3 + 1],
                  w2 = w[(dy + 1) * 3 + 2];
#pragma unroll
      for (int j = 0; j < 8; ++j) acc[j] += w0 * v[j] + w1 * v[j + 1] + w2 * v[j + 2];
    }
    u16x8 ov;
#pragma unroll
    for (int j = 0; j < 8; ++j) {
      sqacc += acc[j] * acc[j];
      ov[j] = f2bf(acc[j]);
    }
    *(u16x8*)(qkv + base + px0) = ov;  // in-place: all reads came from LDS
  }
#pragma unroll
  for (int s = 32; s > 0; s >>= 1) sqacc += __shfl_xor(sqacc, s, 64);
  if (lane == 0) red[wave] = sqacc;
  __syncthreads();
  if (tid == 0) sq[b * 576 + o] = red[0] + red[1] + red[2] + red[3];
}

// ---------------------------------------------------------------------------
// Gram: G_partial[c][d] = sum_n q[c][n]*k[d][n] over a 512-n block (4 waves x
// 128 n each, reduced in-block through LDS). Tile content XOR-swizzled.
// grid (32 chunk-groups, 16 bh); partial[bh][pos][chunk32].
__global__ __launch_bounds__(256) void gram_kernel(
    const u16* __restrict__ qkv, float* __restrict__ partial) {
  __shared__ u16 tiles[4 * 3072];   // per-wave [96][32] bf16 (q 0-47, k 48-95)
  __shared__ float red[4 * 2304];   // per-wave gram copies for in-block reduce
  const int bh = blockIdx.y, b = bh >> 2, h = bh & 3;
  const int g = blockIdx.x;                  // chunk 0..31
  const int wave = threadIdx.x >> 6, lane = threadIdx.x & 63;
  const int n0 = g * 512 + wave * 128;
  const u16* qb = qkv + ((size_t)b * 576 + h * 48) * 16384;
  const u16* kb = qb + (size_t)192 * 16384;
  char* tl = (char*)(tiles + wave * 3072);
  const int l15 = lane & 15, lg = lane >> 4;
  const int swz = (l15 & 3) << 4;
  f32x4 acc[3][3];
#pragma unroll
  for (int i = 0; i < 3; ++i)
#pragma unroll
    for (int j = 0; j < 3; ++j) acc[i][j] = (f32x4){0.f, 0.f, 0.f, 0.f};

  for (int ks = 0; ks < 4; ++ks) {
    const int nn = n0 + ks * 32;
    asm volatile("s_waitcnt lgkmcnt(0)" ::: "memory");
#pragma unroll
    for (int i = 0; i < 6; ++i) {
      const int flat = i * 1024 + lane * 16;
      const int row = flat >> 6, colb = flat & 63;
      const u16* src = (row < 48) ? (qb + (size_t)row * 16384 + nn)
                                  : (kb + (size_t)(row - 48) * 16384 + nn);
      gload_lds16((const char*)src + (colb ^ ((row & 3) << 4)), tl + i * 1024);
    }
    asm volatile("s_waitcnt vmcnt(0)" ::: "memory");
    bf16x8 qf[3], kf[3];
#pragma unroll
    for (int f = 0; f < 3; ++f) {
      qf[f] = *(const bf16x8*)(tl + (f * 16 + l15) * 64 + ((lg * 16) ^ swz));
      kf[f] = *(const bf16x8*)(tl + (48 + f * 16 + l15) * 64 + ((lg * 16) ^ swz));
    }
#pragma unroll
    for (int i = 0; i < 3; ++i)
#pragma unroll
      for (int j = 0; j < 3; ++j)
        acc[i][j] = __builtin_amdgcn_mfma_f32_16x16x32_bf16(qf[i], kf[j],
                                                            acc[i][j], 0, 0, 0);
  }
  // in-block reduce over the 4 waves
  {
    float* rw = red + wave * 2304;
#pragma unroll
    for (int i = 0; i < 3; ++i)
#pragma unroll
      for (int j = 0; j < 3; ++j)
#pragma unroll
        for (int r = 0; r < 4; ++r)
          rw[(i * 16 + lg * 4 + r) * 48 + (j * 16 + l15)] = acc[i][j][r];
  }
  __syncthreads();
#pragma unroll
  for (int it = 0; it < 9; ++it) {
    const int p = it * 256 + threadIdx.x;
    const float s = red[p] + red[2304 + p] + red[4608 + p] + red[6912 + p];
    partial[((size_t)bh * 2304 + p) * 32 + g] = s;
  }
}

// ---------------------------------------------------------------------------
// Wide reduction of gram partials: G[bh*2304+p] = sum over 32 chunks.
__global__ __launch_bounds__(256) void reduce_partial_kernel(
    const float* __restrict__ partial, float* __restrict__ G) {
  const int idx = blockIdx.x * 256 + threadIdx.x;  // 0..36863
  const f32x4* pp = (const f32x4*)(partial + (size_t)idx * 32);
  const f32x4 a = (pp[0] + pp[1]) + (pp[2] + pp[3]) +
                  (pp[4] + pp[5]) + (pp[6] + pp[7]);
  G[idx] = a.x + a.y + a.z + a.w;
}

// ---------------------------------------------------------------------------
// Normalize, softmax, fold attn into projection (reads pre-reduced G).
__global__ __launch_bounds__(256) void softmax_weff_kernel(
    const float* __restrict__ Gin, const float* __restrict__ sq,
    const float* __restrict__ temp, const float* __restrict__ wproj,
    u16* __restrict__ weff) {
  __shared__ float G[2304];        // gram -> attn (in place)
  __shared__ float wp[192 * 49];   // wproj slice, pad 49 (odd bank stride)
  __shared__ float nq[48], nk[48];
  const int bh = blockIdx.x, b = bh >> 2, h = bh & 3;
  const int tid = threadIdx.x;
#pragma unroll
  for (int it = 0; it < 36; ++it) {  // load wproj [192][h*48 .. h*48+48)
    const int j = it * 256 + tid;
    const int o = j / 48, c = j - o * 48;
    wp[o * 49 + c] = wproj[o * 192 + h * 48 + c];
  }
#pragma unroll
  for (int it = 0; it < 9; ++it) {
    const int p = it * 256 + tid;
    G[p] = Gin[(size_t)bh * 2304 + p];
  }
  if (tid < 48) {
    nq[tid] = fmaxf(sqrtf(sq[b * 576 + h * 48 + tid]), 1e-12f);
    nk[tid] = fmaxf(sqrtf(sq[b * 576 + 192 + h * 48 + tid]), 1e-12f);
  }
  __syncthreads();
  if (tid < 48) {  // row softmax (48 rows)
    const int r = tid;
    const float inq = temp[h] / nq[r];
    float L[48];
    float mx = -3.4e38f;
#pragma unroll 4
    for (int d = 0; d < 48; ++d) {
      const float v = G[r * 48 + d] * inq / nk[d];
      L[d] = v;
      mx = fmaxf(mx, v);
    }
    float s = 0.f;
#pragma unroll 4
    for (int d = 0; d < 48; ++d) {
      const float e = __expf(L[d] - mx);
      L[d] = e;
      s += e;
    }
    const float inv = 1.f / s;
#pragma unroll 4
    for (int d = 0; d < 48; ++d) G[r * 48 + d] = L[d] * inv;
  }
  __syncthreads();
  if (tid < 192) {  // Weff row o = tid
    const int o = tid;
    f32x4 acc[12];
#pragma unroll
    for (int dv = 0; dv < 12; ++dv) acc[dv] = (f32x4){0.f, 0.f, 0.f, 0.f};
    for (int c = 0; c < 48; ++c) {
      const float w = wp[o * 49 + c];
      const f32x4* at = (const f32x4*)(G + c * 48);  // broadcast reads
#pragma unroll
      for (int dv = 0; dv < 12; ++dv) acc[dv] += w * at[dv];
    }
    u16* op = weff + ((size_t)b * 192 + o) * 192 + h * 48;
#pragma unroll
    for (int g8 = 0; g8 < 6; ++g8) {
      u16x8 ov;
#pragma unroll
      for (int j = 0; j < 8; ++j) {
        const int d = g8 * 8 + j;
        ov[j] = f2bf(acc[d >> 2][d & 3]);
      }
      *(u16x8*)(op + g8 * 8) = ov;
    }
  }
}

// ---------------------------------------------------------------------------
extern "C" void kernel_launch(void* const* d_in, const int* in_sizes, int n_in,
                              void* d_out, int out_size, void* d_ws,
                              size_t ws_size, hipStream_t stream) {
  (void)in_sizes; (void)n_in; (void)out_size; (void)ws_size;
  const float* x      = (const float*)d_in[0];  // [4][192][128][128]
  const float* w_qkv  = (const float*)d_in[1];  // [576][192]
  const float* w_dw   = (const float*)d_in[2];  // [576][9]
  const float* w_proj = (const float*)d_in[3];  // [192][192]
  const float* temp   = (const float*)d_in[4];  // [4]

  char* ws = (char*)d_ws;
  u16*   qkv     = (u16*)ws;                    // 75,497,472 B
  float* partial = (float*)(ws + 75497472);     //  4,718,592 B [16][2304][32]
  float* G       = (float*)(ws + 80216064);     //    147,456 B
  float* sq      = (float*)(ws + 80363520);     //      9,216 B
  u16*   Wq      = (u16*)(ws + 80372736);       //    221,184 B
  u16*   Weff    = (u16*)(ws + 80593920);       //    294,912 B  (end 80.9 MB)

  // w_qkv -> bf16
  convert_w_kernel<<<dim3(432), 256, 0, stream>>>(w_qkv, Wq, 110592);
  // qkv[b][o][n] = sum_c x[c][n]*Wq[o][c]  (fused x-transpose in staging)
  gemm_bt_kernel<true, true, 9><<<dim3(1024), 256, 0, stream>>>(
      x, Wq, qkv, (size_t)192 * 16384, 0, (size_t)576 * 16384, 16384);
  // depthwise 3x3 in-place + per-channel sum-of-squares
  dwconv_kernel<<<dim3(576, 4), 256, 0, stream>>>(qkv, w_dw, sq);
  // gram partials: 32 chunk-groups per (b,h), in-block wave reduction
  gram_kernel<<<dim3(32, 16), 256, 0, stream>>>(qkv, partial);
  // wide cross-chunk reduction
  reduce_partial_kernel<<<dim3(144), 256, 0, stream>>>(partial, G);
  // normalize + softmax + fold into projection
  softmax_weff_kernel<<<dim3(16), 256, 0, stream>>>(G, sq, temp, w_proj, Weff);
  // out[b][o][n] = sum_c2 v[c2][n]*Weff[o][c2] (fused v-transpose in staging)
  gemm_bt_kernel<false, false, 3><<<dim3(1024), 256, 0, stream>>>(
      qkv + (size_t)384 * 16384, Weff, d_out, (size_t)576 * 16384,
      (size_t)192 * 192, (size_t)192 * 16384, 16384);
}